// Round 4
// baseline (186.748 us; speedup 1.0000x reference)
//
#include <hip/hip_runtime.h>
#include <stdint.h>

#define NUM_HEADS 12
#define DH 64
#define SEQ 2048
#define BATCH 2
#define DM 768
#define NQK 1536  // Q cols [0,768) | K cols [768,1536)
#define LOG2E 1.44269504088896340736f

typedef short short8 __attribute__((ext_vector_type(8)));
typedef short short4_t __attribute__((ext_vector_type(4)));
typedef float f32x4 __attribute__((ext_vector_type(4)));

__device__ __forceinline__ short bf16_rne(float f) {
    union { float f; uint32_t u; } v; v.f = f;
    return (short)((v.u + 0x7FFFu + ((v.u >> 16) & 1u)) >> 16);
}

// ---------------- Kernel 0a: W transpose + bf16 convert ----------------
__global__ __launch_bounds__(256) void wt_kernel(const float* __restrict__ Wq,
                                                 const float* __restrict__ Wk,
                                                 short* __restrict__ Wt) {
    __shared__ float tile[32][33];
    int n0 = blockIdx.x * 32;
    int k0 = blockIdx.y * 32;
    int tx = threadIdx.x & 31;
    int ty = threadIdx.x >> 5;
    const float* src = (n0 < DM) ? Wq : Wk;
    int nn0 = (n0 < DM) ? n0 : n0 - DM;
#pragma unroll
    for (int j = 0; j < 4; ++j) {
        int k = ty + 8 * j;
        tile[k][tx] = src[(size_t)(k0 + k) * DM + nn0 + tx];
    }
    __syncthreads();
#pragma unroll
    for (int j = 0; j < 4; ++j) {
        int n = ty + 8 * j;
        Wt[(size_t)(n0 + n) * DM + k0 + tx] = bf16_rne(tile[tx][n]);
    }
}

// ---------------- Kernel 0b: x -> bf16 ----------------
__global__ __launch_bounds__(256) void xb_kernel(const float* __restrict__ x,
                                                 short* __restrict__ Xb) {
    int i = (blockIdx.x * 256 + threadIdx.x) * 4;
    f32x4 v = *(const f32x4*)(x + i);
    short4_t s;
#pragma unroll
    for (int j = 0; j < 4; ++j) s[j] = bf16_rne(v[j]);
    *(short4_t*)(Xb + i) = s;
}

// ---------------- Kernel 0c: mask -> bitmask ----------------
__global__ __launch_bounds__(256) void mpack_kernel(const int* __restrict__ mask,
                                                    unsigned long long* __restrict__ Mb) {
    int wid = (blockIdx.x * 256 + threadIdx.x) >> 6;
    int lane = threadIdx.x & 63;
    size_t base = (size_t)wid * 8;
#pragma unroll
    for (int i = 0; i < 8; ++i) {
        size_t w = base + i;
        int v = mask[w * 64 + lane];
        unsigned long long bal = __ballot(v != 0);
        if (lane == 0) Mb[w] = bal;
    }
}

// ---------------- Kernel 1: projection GEMM (128x64 tile, BK=32, dbuf) ----------------
__global__ __launch_bounds__(256) void proj_kernel(const short* __restrict__ Xb,
                                                   const short* __restrict__ Wt,
                                                   const float* __restrict__ bq,
                                                   const float* __restrict__ bk,
                                                   short* __restrict__ QK) {
    __shared__ short As[2][128 * 40];
    __shared__ short Bs[2][64 * 40];
    const int m0 = blockIdx.x * 128;
    const int n0 = blockIdx.y * 64;
    const int t = threadIdx.x;
    const int lane = t & 63;
    const int w = t >> 6;
    const int wr = w >> 1, wc = w & 1;  // wave -> (64-row, 32-col) quadrant
    const int lr = lane & 15;
    const int lk = lane >> 4;

    // staging coordinates
    const int ar0 = t >> 2, ach = t & 3;      // A slots t and t+256 -> rows ar0, ar0+64
    const int br0 = t >> 2, bch = t & 3;      // B slot t -> row br0 (0..63)

    f32x4 acc[4][2] = {};
    short8 ra0, ra1, rb;

#define PROJ_LOAD(K0)                                                              \
    ra0 = *(const short8*)&Xb[(size_t)(m0 + ar0) * DM + (K0) + ach * 8];           \
    ra1 = *(const short8*)&Xb[(size_t)(m0 + ar0 + 64) * DM + (K0) + ach * 8];      \
    rb  = *(const short8*)&Wt[(size_t)(n0 + br0) * DM + (K0) + bch * 8];

#define PROJ_WRITE(BUF)                                                            \
    *(short8*)&As[BUF][ar0 * 40 + ach * 8] = ra0;                                  \
    *(short8*)&As[BUF][(ar0 + 64) * 40 + ach * 8] = ra1;                           \
    *(short8*)&Bs[BUF][br0 * 40 + bch * 8] = rb;

    PROJ_LOAD(0)
    PROJ_WRITE(0)
    __syncthreads();

    int cur = 0;
    for (int s = 0; s < DM / 32; ++s) {
        if (s < DM / 32 - 1) { PROJ_LOAD((s + 1) * 32) }
        short8 a[4], bb[2];
#pragma unroll
        for (int m = 0; m < 4; ++m)
            a[m] = *(short8*)&As[cur][(wr * 64 + m * 16 + lr) * 40 + lk * 8];
#pragma unroll
        for (int n = 0; n < 2; ++n)
            bb[n] = *(short8*)&Bs[cur][(wc * 32 + n * 16 + lr) * 40 + lk * 8];
#pragma unroll
        for (int m = 0; m < 4; ++m)
#pragma unroll
            for (int n = 0; n < 2; ++n)
                acc[m][n] = __builtin_amdgcn_mfma_f32_16x16x32_bf16(a[m], bb[n], acc[m][n], 0, 0, 0);
        if (s < DM / 32 - 1) { PROJ_WRITE(cur ^ 1) }
        __syncthreads();
        cur ^= 1;
    }

    const int orow = m0 + wr * 64;
    const int ocol = n0 + wc * 32;
#pragma unroll
    for (int m = 0; m < 4; ++m) {
#pragma unroll
        for (int n = 0; n < 2; ++n) {
            int col = ocol + n * 16 + lr;
            float bias = (col < DM) ? bq[col] : bk[col - DM];
            float scale = (col < DM) ? 0.125f * LOG2E : 1.0f;
#pragma unroll
            for (int r = 0; r < 4; ++r) {
                int row = orow + m * 16 + lk * 4 + r;
                QK[(size_t)row * NQK + col] = bf16_rne((acc[m][n][r] + bias) * scale);
            }
        }
    }
#undef PROJ_LOAD
#undef PROJ_WRITE
}

// ---------------- Kernel 2: scores + softmax (swapped MFMA, dbuf, two-pass) ----------------
// mfma(K, Q): lane holds ONE q row (lr) and 16 k-scores (4 nf x 4 reg, k consecutive in reg)
__global__ __launch_bounds__(256) void attn_kernel(const short* __restrict__ QK,
                                                   const unsigned long long* __restrict__ Mb,
                                                   float* __restrict__ out) {
    __shared__ short Ks[2][64 * 72];
    const int qblk = blockIdx.x;
    const int h = blockIdx.y;
    const int b = blockIdx.z;
    const int t = threadIdx.x;
    const int lane = t & 63;
    const int w = t >> 6;
    const int lr = lane & 15;   // q row within wave tile; also key row for A-frag loads
    const int lk = lane >> 4;   // dh chunk for frags; k sub-block for output
    const int wq = qblk * 64 + w * 16;
    const int q = wq + lr;      // this lane's q row

    // Q fragments (B-operand): col=lr -> q row; pre-scaled by 0.125*log2e
    short8 aq0 = *(const short8*)&QK[(size_t)(b * SEQ + q) * NQK + h * DH + lk * 8];
    short8 aq1 = *(const short8*)&QK[(size_t)(b * SEQ + q) * NQK + h * DH + 32 + lk * 8];

    const size_t mrow = (size_t)b * SEQ * (SEQ / 64) + (size_t)q * 32;
    const int srow = t >> 3, sch = t & 7;  // staging: rows srow, srow+32, chunk sch
    short8 rs0, rs1;

#define ATT_LOAD(KT)                                                                          \
    rs0 = *(const short8*)&QK[(size_t)(b * SEQ + (KT) + srow) * NQK + DM + h * DH + sch * 8]; \
    rs1 = *(const short8*)&QK[(size_t)(b * SEQ + (KT) + srow + 32) * NQK + DM + h * DH + sch * 8];

#define ATT_WRITE(BUF)                                                                        \
    *(short8*)&Ks[BUF][srow * 72 + sch * 8] = rs0;                                            \
    *(short8*)&Ks[BUF][(srow + 32) * 72 + sch * 8] = rs1;

    // ---- pass A: per-lane sum of exp2 over its 16 k's per tile ----
    float lsum = 0.0f;
    ATT_LOAD(0)
    ATT_WRITE(0)
    __syncthreads();
    int cur = 0;
    for (int kt = 0; kt < SEQ; kt += 64) {
        if (kt + 64 < SEQ) { ATT_LOAD(kt + 64) }
        unsigned long long mbs = Mb[mrow + (kt >> 6)] >> (lk * 4);
#pragma unroll
        for (int nf = 0; nf < 4; ++nf) {
            short8 k0 = *(short8*)&Ks[cur][(nf * 16 + lr) * 72 + lk * 8];
            short8 k1 = *(short8*)&Ks[cur][(nf * 16 + lr) * 72 + 32 + lk * 8];
            f32x4 a = {0.f, 0.f, 0.f, 0.f};
            a = __builtin_amdgcn_mfma_f32_16x16x32_bf16(k0, aq0, a, 0, 0, 0);
            a = __builtin_amdgcn_mfma_f32_16x16x32_bf16(k1, aq1, a, 0, 0, 0);
#pragma unroll
            for (int r = 0; r < 4; ++r) {
                float e = __builtin_amdgcn_exp2f(a[r]);
                lsum += ((mbs >> (nf * 16 + r)) & 1ull) ? e : 0.f;
            }
        }
        if (kt + 64 < SEQ) { ATT_WRITE(cur ^ 1) }
        __syncthreads();
        cur ^= 1;
    }

    // reduce over the 4 lk lanes sharing this q row
    lsum += __shfl_xor(lsum, 16, 64);
    lsum += __shfl_xor(lsum, 32, 64);
    float li = -__log2f(lsum);  // fold normalization into MFMA C-operand
    f32x4 li4 = {li, li, li, li};

    // ---- pass B: recompute, normalize via acc-init, dwordx4 stores ----
    const size_t orow = ((size_t)((b * NUM_HEADS + h) * SEQ) + q) * SEQ;
    ATT_LOAD(0)
    ATT_WRITE(0)
    __syncthreads();
    cur = 0;
    for (int kt = 0; kt < SEQ; kt += 64) {
        if (kt + 64 < SEQ) { ATT_LOAD(kt + 64) }
        unsigned long long mbs = Mb[mrow + (kt >> 6)] >> (lk * 4);
#pragma unroll
        for (int nf = 0; nf < 4; ++nf) {
            short8 k0 = *(short8*)&Ks[cur][(nf * 16 + lr) * 72 + lk * 8];
            short8 k1 = *(short8*)&Ks[cur][(nf * 16 + lr) * 72 + 32 + lk * 8];
            f32x4 a = __builtin_amdgcn_mfma_f32_16x16x32_bf16(k0, aq0, li4, 0, 0, 0);
            a = __builtin_amdgcn_mfma_f32_16x16x32_bf16(k1, aq1, a, 0, 0, 0);
            f32x4 p;
#pragma unroll
            for (int r = 0; r < 4; ++r) {
                float e = __builtin_amdgcn_exp2f(a[r]);
                p[r] = ((mbs >> (nf * 16 + r)) & 1ull) ? e : 0.f;
            }
            *(f32x4*)&out[orow + kt + nf * 16 + lk * 4] = p;
        }
        if (kt + 64 < SEQ) { ATT_WRITE(cur ^ 1) }
        __syncthreads();
        cur ^= 1;
    }
#undef ATT_LOAD
#undef ATT_WRITE
}

extern "C" void kernel_launch(void* const* d_in, const int* in_sizes, int n_in,
                              void* d_out, int out_size, void* d_ws, size_t ws_size,
                              hipStream_t stream) {
    (void)in_sizes; (void)n_in; (void)out_size; (void)ws_size;
    const float* x = (const float*)d_in[0];
    const int* mask = (const int*)d_in[1];
    const float* Wq = (const float*)d_in[2];
    const float* bq = (const float*)d_in[3];
    const float* Wk = (const float*)d_in[4];
    const float* bk = (const float*)d_in[5];
    float* out = (float*)d_out;

    short* Wt = (short*)d_ws;                           // 1536*768 bf16
    short* Xb = Wt + (size_t)NQK * DM;                  // 4096*768 bf16
    short* QK = Xb + (size_t)BATCH * SEQ * DM;          // 4096*1536 bf16
    unsigned long long* Mb =
        (unsigned long long*)(QK + (size_t)BATCH * SEQ * NQK);  // 131072 u64

    wt_kernel<<<dim3(NQK / 32, DM / 32), 256, 0, stream>>>(Wq, Wk, Wt);
    xb_kernel<<<dim3((BATCH * SEQ * DM) / (256 * 4)), 256, 0, stream>>>(x, Xb);
    mpack_kernel<<<dim3((BATCH * SEQ * SEQ / 64) / 32), 256, 0, stream>>>(mask, Mb);
    proj_kernel<<<dim3(BATCH * SEQ / 128, NQK / 64), 256, 0, stream>>>(Xb, Wt, bq, bk, QK);
    attn_kernel<<<dim3(SEQ / 64, NUM_HEADS, BATCH), 256, 0, stream>>>(QK, Mb, out);
}